// Round 14
// baseline (69.081 us; speedup 1.0000x reference)
//
#include <hip/hip_runtime.h>

// vol:  [B=8, D=64, H=128, W=128, C=2] f32
// flow: [B, D, H, W, 3] f32 (displacements)
// out:  [B, D, H, W, C] f32
//
// R14 = R11 geometry + global_load_lds DMA staging (no reg round-trip, no
// ds_writes, no pad).
//  - 256 persistent blocks (8b x 32 h-tiles) x 1024 thr; 16 d-tile iters.
//  - LDS: 12 circular plane-slots x 12 h-rows x 256 floats (interleaved x,y)
//    = 147,456 B. slot = plane mod 12 (db12 carried incrementally).
//  - staging: one wave DMAs one vol row (64 lanes x 16 B, linear dest) --
//    exactly the global_load_lds wave-uniform-base constraint (m104).
//    Rotation: 48 rows = 3 DMA/wave, issued between the two barriers
//    together with the next-iter flow prefetch; one vmcnt drain covers both.
//  - gather: 2 voxels/thread, wave-uniform (d,h), lanes = 64 consecutive W;
//    8 x float2 LDS reads/voxel (b64, 4-way pair floor).
//  - |jitter| beyond halo (P~1e-4): exec-masked global fallback.

typedef float f32x4 __attribute__((ext_vector_type(4)));
typedef f32x4 __attribute__((aligned(8))) f32x4a;

#define SLOTF 3072     // floats per plane-slot: 12 rows x 256
#define NSLOT 12

__device__ __forceinline__ void dma_row16(const float* g, float* l) {
    // lane i transfers 16B from g (per-lane addr) to ldsbase + i*16
    __builtin_amdgcn_global_load_lds(
        (const __attribute__((address_space(1))) void*)g,
        (__attribute__((address_space(3))) void*)l,
        16, 0, 0);
}

__device__ __forceinline__ void sample_store(
    const float* __restrict__ vb, const float* lds, int db12,
    float f0, float f1, float f2,
    int d, int h, int w, int dbase, int hbase,
    float* __restrict__ out, size_t vox)
{
    float cd = fminf(fmaxf((float)d + f0, 0.0f), 63.0f);
    float ch = fminf(fmaxf((float)h + f1, 0.0f), 127.0f);
    float cw = fminf(fmaxf((float)w + f2, 0.0f), 127.0f);
    int ld = (int)cd; ld = (ld > 62) ? 62 : ld;
    int lh = (int)ch; lh = (lh > 126) ? 126 : lh;
    int lw = (int)cw; lw = (lw > 126) ? 126 : lw;
    const float wd = cd - (float)ld;
    const float wh = ch - (float)lh;
    const float ww = cw - (float)lw;
    const int i_d = ld - dbase;   // LDS path needs <= 10 (ld+1 in window)
    const int i_h = lh - hbase;   // <= 10

    float2 p00l, p00r, p01l, p01r, p10l, p10r, p11l, p11r;
    if (__builtin_expect(((unsigned)i_d <= 10u) & ((unsigned)i_h <= 10u), 1)) {
        int m0 = db12 + i_d; if (m0 >= NSLOT) m0 -= NSLOT;
        int m1 = m0 + 1;     if (m1 == NSLOT) m1 = 0;
        const int eA = m0 * SLOTF + (i_h << 8) + (lw << 1);
        const int eB = m1 * SLOTF + (i_h << 8) + (lw << 1);
        p00l = *(const float2*)&lds[eA];
        p00r = *(const float2*)&lds[eA + 2];
        p01l = *(const float2*)&lds[eA + 256];
        p01r = *(const float2*)&lds[eA + 258];
        p10l = *(const float2*)&lds[eB];
        p10r = *(const float2*)&lds[eB + 2];
        p11l = *(const float2*)&lds[eB + 256];
        p11r = *(const float2*)&lds[eB + 258];
    } else {
        const int o = (ld << 15) + (lh << 8) + (lw << 1);
        const f32x4 a00 = *(const f32x4a*)(vb + o);
        const f32x4 a01 = *(const f32x4a*)(vb + o + 256);
        const f32x4 a10 = *(const f32x4a*)(vb + o + 32768);
        const f32x4 a11 = *(const f32x4a*)(vb + o + 33024);
        p00l = make_float2(a00.x, a00.y); p00r = make_float2(a00.z, a00.w);
        p01l = make_float2(a01.x, a01.y); p01r = make_float2(a01.z, a01.w);
        p10l = make_float2(a10.x, a10.y); p10r = make_float2(a10.z, a10.w);
        p11l = make_float2(a11.x, a11.y); p11r = make_float2(a11.z, a11.w);
    }

    const float wd0 = 1.0f - wd, wh0 = 1.0f - wh;
    const float ww1 = ww, ww0 = 1.0f - ww;
    const float w00 = wd0 * wh0, w01 = wd0 * wh;
    const float w10 = wd * wh0,  w11 = wd * wh;

    const float ox = (p00l.x * w00 + p01l.x * w01 + p10l.x * w10 + p11l.x * w11) * ww0
                   + (p00r.x * w00 + p01r.x * w01 + p10r.x * w10 + p11r.x * w11) * ww1;
    const float oy = (p00l.y * w00 + p01l.y * w01 + p10l.y * w10 + p11l.y * w11) * ww0
                   + (p00r.y * w00 + p01r.y * w01 + p10r.y * w10 + p11r.y * w11) * ww1;

    *(float2*)(out + vox * 2) = make_float2(ox, oy);
}

__global__ __launch_bounds__(1024, 4) void st_dma_kernel(
    const float* __restrict__ vol,
    const float* __restrict__ flow,
    float* __restrict__ out)
{
    __shared__ float lds[NSLOT * SLOTF];   // 147,456 B

    const int t    = threadIdx.x;
    const int bid  = blockIdx.x;           // b*32 + htile
    const int h0    = (bid & 31) << 2;
    const int b     = bid >> 5;
    const int hbase = h0 - 4;

    const float* vb = vol + ((size_t)b << 21);

    const int lane = t & 63;
    const int wid  = t >> 6;        // 0..15, wave id (uniform)
    const int dr   = wid >> 2;      // 0..3: d offset within tile
    const int hh   = h0 + (wid & 3);

    // ---- initial stage: planes [-4..7] -> slots (i_d+8)%12; 144 rows ----
    {
#pragma unroll
        for (int j = 0; j < 9; ++j) {
            const int rr  = wid * 9 + j;           // 0..143
            const int i_d = rr / 12;
            const int i_h = rr - i_d * 12;
            const int gd  = max(i_d - 4, 0);
            const int gh  = min(max(hbase + i_h, 0), 127);
            int sl = i_d + 8; if (sl >= NSLOT) sl -= NSLOT;
            dma_row16(vb + ((((size_t)gd << 7) + gh) << 8) + (lane << 2),
                      &lds[sl * SLOTF + (i_h << 8)]);
        }
    }

    // prologue flow (dt=0)
    float cfA0, cfA1, cfA2, cfB0, cfB1, cfB2;
    {
        const size_t rowbase = ((((size_t)((b << 6) | dr) << 7) | hh) << 7);
        const float* fA = flow + (rowbase + lane) * 3;
        cfA0 = fA[0]; cfA1 = fA[1]; cfA2 = fA[2];
        const float* fB = flow + (rowbase + lane + 64) * 3;
        cfB0 = fB[0]; cfB1 = fB[1]; cfB2 = fB[2];
    }
    __syncthreads();   // drains DMA (vmcnt) + makes window visible

    int db12 = 8;      // (dbase = -4) mod 12
    for (int dt = 0; dt < 16; ++dt) {
        const int d0    = dt << 2;
        const int dbase = d0 - 4;
        const int d     = d0 + dr;
        const size_t rowbase = ((((size_t)((b << 6) | d) << 7) | hh) << 7);
        const size_t voxA = rowbase + lane;

        // ---- gather current tile ----
        sample_store(vb, lds, db12, cfA0, cfA1, cfA2, d, hh, lane,
                     dbase, hbase, out, voxA);
        sample_store(vb, lds, db12, cfB0, cfB1, cfB2, d, hh, lane + 64,
                     dbase, hbase, out, voxA + 64);

        // ---- rotate window: DMA 4 new planes + prefetch next flow ----
        if (dt < 15) {
            __syncthreads();                       // all gathers done
#pragma unroll
            for (int j = 0; j < 3; ++j) {
                const int rr   = wid * 3 + j;      // 0..47
                const int i_d4 = rr / 12;
                const int i_h  = rr - i_d4 * 12;
                const int p    = d0 + 8 + i_d4;    // new planes d0+8..d0+11
                const int gd   = (p > 63) ? 63 : p;
                const int gh   = min(max(hbase + i_h, 0), 127);
                int sl = db12 + i_d4; if (sl >= NSLOT) sl -= NSLOT;  // p mod 12
                dma_row16(vb + ((((size_t)gd << 7) + gh) << 8) + (lane << 2),
                          &lds[sl * SLOTF + (i_h << 8)]);
            }
            // next-iter flow, in flight alongside the DMA
            const int dn = d + 4;
            const size_t rbn = ((((size_t)((b << 6) | dn) << 7) | hh) << 7);
            const float* fA = flow + (rbn + lane) * 3;
            cfA0 = fA[0]; cfA1 = fA[1]; cfA2 = fA[2];
            const float* fB = flow + (rbn + lane + 64) * 3;
            cfB0 = fB[0]; cfB1 = fB[1]; cfB2 = fB[2];
            __syncthreads();                       // one vmcnt drain: DMA + flow
            db12 += 4; if (db12 >= NSLOT) db12 -= NSLOT;
        }
    }
}

extern "C" void kernel_launch(void* const* d_in, const int* in_sizes, int n_in,
                              void* d_out, int out_size, void* d_ws, size_t ws_size,
                              hipStream_t stream) {
    const float* vol  = (const float*)d_in[0];
    const float* flow = (const float*)d_in[1];
    float* out = (float*)d_out;

    // 8 batches x 32 h-tiles = 256 persistent blocks (1 per CU)
    hipLaunchKernelGGL(st_dma_kernel, dim3(256), dim3(1024), 0, stream,
                       vol, flow, out);
}